// Round 3
// baseline (842.769 us; speedup 1.0000x reference)
//
#include <hip/hip_runtime.h>
#include <hip/hip_bf16.h>

#define HID   128
#define OUTD  64
#define NPROD 100000
#define NCUST 50000
#define EPP   800000
#define EPC   800000
#define ELB   400000

typedef __bf16 bf16x8 __attribute__((ext_vector_type(8)));
typedef float  f32x4  __attribute__((ext_vector_type(4)));
typedef unsigned short u16;

__device__ __forceinline__ float b2f(u16 u) {
  unsigned int v = ((unsigned int)u) << 16;
  float f; __builtin_memcpy(&f, &v, 4); return f;
}
__device__ __forceinline__ u16 f2b(float f) {
  __hip_bfloat16 h = __float2bfloat16(f);
  u16 u; __builtin_memcpy(&u, &h, 2); return u;
}

union Pack8 { u16 u[8]; int4 v; };

// XOR-swizzled LDS index (elements). Rows of 128 bf16 (256 B); 16 B chunks
// swizzled by row&15 so column-direction ds_read_b128 lands 2-way max (free).
__device__ __forceinline__ int sidx(int row, int chunk) {
  return row * HID + ((chunk ^ (row & 15)) << 3);
}

// ---------------- CSR build (order-free bucketing) ----------------
__global__ __launch_bounds__(256) void k_hist(const int* __restrict__ dst, int E,
                                              int* __restrict__ cnt) {
  int e = blockIdx.x * 256 + threadIdx.x;
  if (e < E) atomicAdd(&cnt[dst[e]], 1);
}

__global__ __launch_bounds__(256) void k_offsets(const int* __restrict__ cnt, int n,
                                                 int* __restrict__ start,
                                                 int* __restrict__ fill,
                                                 int* __restrict__ ctr) {
  int i = blockIdx.x * 256 + threadIdx.x;
  if (i < n) {
    int s = atomicAdd(ctr, cnt[i]);   // order-free contiguous range per node
    start[i] = s;
    fill[i]  = s;
  }
}

__global__ __launch_bounds__(256) void k_fill(const int* __restrict__ src,
                                              const int* __restrict__ dst, int E,
                                              int* __restrict__ fill,
                                              int* __restrict__ esrc) {
  int e = blockIdx.x * 256 + threadIdx.x;
  if (e < E) {
    int p = atomicAdd(&fill[dst[e]], 1);
    esrc[p] = src[e];
  }
}

// ---------------- mean aggregation: one wave per destination node ----------------
// F32 variant reads fp32 features (the raw inputs); else bf16 intermediates.
// Mean accumulates in fp32 either way; output is bf16.
template <bool F32>
__global__ __launch_bounds__(256) void k_agg(const int* __restrict__ esrc,
                                             const int* __restrict__ start,
                                             const int* __restrict__ cnt,
                                             const void* __restrict__ xv,
                                             u16* __restrict__ outm, int n_dst) {
  int wave = blockIdx.x * 4 + (threadIdx.x >> 6);
  int lane = threadIdx.x & 63;
  if (wave >= n_dst) return;
  int s0 = start[wave], c = cnt[wave];
  float a0 = 0.f, a1 = 0.f;
  for (int j = 0; j < c; j += 64) {
    int nch = min(64, c - j);
    int eid = (lane < nch) ? esrc[s0 + j + lane] : 0;
    for (int k = 0; k < nch; ++k) {
      int s = __shfl(eid, k, 64);
      if (F32) {
        const float* x = (const float*)xv;
        float2 v = *(const float2*)(x + (size_t)s * HID + 2 * lane);
        a0 += v.x; a1 += v.y;
      } else {
        const u16* x = (const u16*)xv;
        ushort2 v = *(const ushort2*)(x + (size_t)s * HID + 2 * lane);
        a0 += b2f(v.x); a1 += b2f(v.y);
      }
    }
  }
  float inv = 1.0f / (float)max(c, 1);
  u16* o = outm + (size_t)wave * HID + 2 * lane;
  ushort2 ov; ov.x = f2b(a0 * inv); ov.y = f2b(a1 * inv);
  *(ushort2*)o = ov;
}

// ---------------- fused (dual-K) GEMM: out = act(A1@W1^T [+ A2@W2^T] + bias) ----------------
// A1: bf16 [M,128]; A2: bf16 or fp32 per A2F; W*: fp32 [BN,128] (converted in
// staging); bias fp32 [BN]; out bf16 [M,BN]. Block tile 64xBN, 4 waves in N.
// LDS: 16 KB (sA) + BN*256 B (sW) <= 48 KB. In-place (out==A2) safe: each
// block reads only the rows it writes.
template <int BN, bool DUAL, bool RELU, bool A2F>
__global__ __launch_bounds__(256) void k_gemm(const u16* __restrict__ A1,
                                              const float* __restrict__ W1,
                                              const void* __restrict__ A2v,
                                              const float* __restrict__ W2,
                                              const float* __restrict__ bias,
                                              u16* __restrict__ out, int M) {
  __shared__ __align__(16) u16 sA[64 * HID];
  __shared__ __align__(16) u16 sW[BN * HID];
  const int tid  = threadIdx.x;
  const int lane = tid & 63;
  const int wave = tid >> 6;          // 0..3 -> N-group
  const int q    = lane >> 4;
  const int r16  = lane & 15;
  const int m0   = blockIdx.x * 64;
  constexpr int NT = BN / 64;         // 16-col tiles per wave

  f32x4 acc[4][NT];
  #pragma unroll
  for (int i = 0; i < 4; ++i)
    #pragma unroll
    for (int j = 0; j < NT; ++j) {
      acc[i][j][0] = 0.f; acc[i][j][1] = 0.f; acc[i][j][2] = 0.f; acc[i][j][3] = 0.f;
    }

  #pragma unroll
  for (int phase = 0; phase < (DUAL ? 2 : 1); ++phase) {
    const float* W = phase ? W2 : W1;
    if (phase) __syncthreads();       // phase-0 MFMA reads done before restage
    // stage A tile (64 rows x 16 chunks of 8 elems), guarded at ragged tail
    #pragma unroll
    for (int i = 0; i < 4; ++i) {
      int idx = i * 256 + tid;
      int rr = idx >> 4, c8 = idx & 15;
      int gr = m0 + rr;
      Pack8 p; p.v = make_int4(0, 0, 0, 0);
      if (gr < M) {
        if (phase == 0 || !A2F) {
          const u16* A = phase ? (const u16*)A2v : A1;
          p.v = *(const int4*)(A + (size_t)gr * HID + c8 * 8);
        } else {
          const float* A = (const float*)A2v;
          const float* s = A + (size_t)gr * HID + c8 * 8;
          #pragma unroll
          for (int j = 0; j < 8; ++j) p.u[j] = f2b(s[j]);
        }
      }
      *(int4*)(sA + sidx(rr, c8)) = p.v;
    }
    // stage W tile (BN rows x 16 chunks), fp32 -> bf16
    #pragma unroll
    for (int i = 0; i < BN / 16; ++i) {
      int idx = i * 256 + tid;
      int rr = idx >> 4, c8 = idx & 15;
      const float* s = W + (size_t)rr * HID + c8 * 8;
      Pack8 p;
      #pragma unroll
      for (int j = 0; j < 8; ++j) p.u[j] = f2b(s[j]);
      *(int4*)(sW + sidx(rr, c8)) = p.v;
    }
    __syncthreads();
    #pragma unroll
    for (int ks = 0; ks < 4; ++ks) {
      int chunk = ks * 4 + q;         // k = ks*32 + q*8 + j
      bf16x8 a[4], b[NT];
      #pragma unroll
      for (int mi = 0; mi < 4; ++mi)
        a[mi] = *(const bf16x8*)(sA + sidx(mi * 16 + r16, chunk));
      #pragma unroll
      for (int ni = 0; ni < NT; ++ni)
        b[ni] = *(const bf16x8*)(sW + sidx(wave * (16 * NT) + ni * 16 + r16, chunk));
      #pragma unroll
      for (int mi = 0; mi < 4; ++mi)
        #pragma unroll
        for (int ni = 0; ni < NT; ++ni)
          acc[mi][ni] = __builtin_amdgcn_mfma_f32_16x16x32_bf16(a[mi], b[ni], acc[mi][ni], 0, 0, 0);
    }
  }
  // epilogue: fp32 bias (+ReLU), bf16 store. C/D: col=lane&15, row=(lane>>4)*4+r.
  #pragma unroll
  for (int ni = 0; ni < NT; ++ni) {
    int col = wave * (16 * NT) + ni * 16 + r16;
    float bv = bias[col];
    #pragma unroll
    for (int mi = 0; mi < 4; ++mi) {
      #pragma unroll
      for (int r = 0; r < 4; ++r) {
        int gr = m0 + mi * 16 + q * 4 + r;
        if (gr < M) {
          float v = acc[mi][ni][r] + bv;
          if (RELU) v = fmaxf(v, 0.f);
          out[(size_t)gr * BN + col] = f2b(v);
        }
      }
    }
  }
}

// ---------------- edge decoder: out = w2 . relu(W1 @ [zc[row]|zp[col]] + b1) + b2 ----------------
// zc/zp bf16 [.,64]; W1 fp32 [64,128]; b1,w2 fp32 [64]; b2 fp32 [1]; out fp32 [ELB].
__global__ __launch_bounds__(256) void k_decoder(const u16* __restrict__ zc,
                                                 const u16* __restrict__ zp,
                                                 const int* __restrict__ eli,
                                                 const float* __restrict__ W1,
                                                 const float* __restrict__ b1,
                                                 const float* __restrict__ w2,
                                                 const float* __restrict__ b2,
                                                 float* __restrict__ out) {
  __shared__ __align__(16) u16 sH[64 * HID];
  __shared__ __align__(16) u16 sW[64 * HID];
  const int tid  = threadIdx.x;
  const int lane = tid & 63;
  const int wave = tid >> 6;
  const int q    = lane >> 4;
  const int r16  = lane & 15;
  const int e0   = blockIdx.x * 64;
  // stage W1 (64x128) fp32 -> bf16
  #pragma unroll
  for (int i = 0; i < 4; ++i) {
    int idx = i * 256 + tid;
    int rr = idx >> 4, c8 = idx & 15;
    const float* s = W1 + (size_t)rr * HID + c8 * 8;
    Pack8 p;
    #pragma unroll
    for (int j = 0; j < 8; ++j) p.u[j] = f2b(s[j]);
    *(int4*)(sW + sidx(rr, c8)) = p.v;
  }
  // stage H: 64 edges x (64 zc | 64 zp), bf16 gather
  #pragma unroll
  for (int i = 0; i < 4; ++i) {
    int idx = i * 256 + tid;
    int rr = idx >> 4, c8 = idx & 15;
    int e = e0 + rr;
    int4 v = make_int4(0, 0, 0, 0);
    if (e < ELB) {
      if (c8 < 8) {
        int rI = eli[e];
        v = *(const int4*)(zc + (size_t)rI * OUTD + c8 * 8);
      } else {
        int cI = eli[ELB + e];
        v = *(const int4*)(zp + (size_t)cI * OUTD + (c8 - 8) * 8);
      }
    }
    *(int4*)(sH + sidx(rr, c8)) = v;
  }
  __syncthreads();
  f32x4 acc[4];
  #pragma unroll
  for (int ni = 0; ni < 4; ++ni) { acc[ni][0]=0.f; acc[ni][1]=0.f; acc[ni][2]=0.f; acc[ni][3]=0.f; }
  #pragma unroll
  for (int ks = 0; ks < 4; ++ks) {
    int chunk = ks * 4 + q;
    bf16x8 a = *(const bf16x8*)(sH + sidx(wave * 16 + r16, chunk));
    #pragma unroll
    for (int ni = 0; ni < 4; ++ni) {
      bf16x8 b = *(const bf16x8*)(sW + sidx(ni * 16 + r16, chunk));
      acc[ni] = __builtin_amdgcn_mfma_f32_16x16x32_bf16(a, b, acc[ni], 0, 0, 0);
    }
  }
  float vs[4] = {0.f, 0.f, 0.f, 0.f};
  #pragma unroll
  for (int ni = 0; ni < 4; ++ni) {
    int col = ni * 16 + r16;
    float bb = b1[col];
    float ww = w2[col];
    #pragma unroll
    for (int r = 0; r < 4; ++r) {
      float t = fmaxf(acc[ni][r] + bb, 0.f);
      vs[r] += t * ww;
    }
  }
  #pragma unroll
  for (int r = 0; r < 4; ++r) {
    vs[r] += __shfl_xor(vs[r], 1, 64);
    vs[r] += __shfl_xor(vs[r], 2, 64);
    vs[r] += __shfl_xor(vs[r], 4, 64);
    vs[r] += __shfl_xor(vs[r], 8, 64);
  }
  if (r16 == 0) {
    float bb2 = b2[0];
    #pragma unroll
    for (int r = 0; r < 4; ++r) {
      int e = e0 + wave * 16 + q * 4 + r;
      if (e < ELB) out[e] = vs[r] + bb2;
    }
  }
}

extern "C" void kernel_launch(void* const* d_in, const int* in_sizes, int n_in,
                              void* d_out, int out_size, void* d_ws, size_t ws_size,
                              hipStream_t stream) {
  const float* x_prod = (const float*)d_in[0];
  const float* x_cust = (const float*)d_in[1];
  const int* ei_pp    = (const int*)d_in[2];
  const int* ei_pc    = (const int*)d_in[3];
  const int* eli      = (const int*)d_in[4];

  // Input-order detection: dict order has it_W1r (16384 elems) at index 6;
  // reference-signature order has it_b1 (128) there.
  const float *it_W1l, *it_W1r, *it_b1, *it_W2l, *it_W2r, *it_b2, *it_Wlin, *it_blin;
  const float *us_W1l, *us_W1r, *us_b1, *us_W2l, *us_W2r, *us_b2;
  const float *us_W3l, *us_W3r, *us_b3, *us_Wlin, *us_blin;
  if (in_sizes[6] == 128) {   // signature order (Wl, b, Wr)
    it_W1l  = (const float*)d_in[5];  it_b1   = (const float*)d_in[6];  it_W1r  = (const float*)d_in[7];
    it_W2l  = (const float*)d_in[8];  it_b2   = (const float*)d_in[9];  it_W2r  = (const float*)d_in[10];
    it_Wlin = (const float*)d_in[11]; it_blin = (const float*)d_in[12];
    us_W1l  = (const float*)d_in[13]; us_b1   = (const float*)d_in[14]; us_W1r  = (const float*)d_in[15];
    us_W2l  = (const float*)d_in[16]; us_b2   = (const float*)d_in[17]; us_W2r  = (const float*)d_in[18];
    us_W3l  = (const float*)d_in[19]; us_b3   = (const float*)d_in[20]; us_W3r  = (const float*)d_in[21];
    us_Wlin = (const float*)d_in[22]; us_blin = (const float*)d_in[23];
  } else {                    // setup_inputs dict order (Wl, Wr, b)
    it_W1l  = (const float*)d_in[5];  it_W1r  = (const float*)d_in[6];  it_b1   = (const float*)d_in[7];
    it_W2l  = (const float*)d_in[8];  it_W2r  = (const float*)d_in[9];  it_b2   = (const float*)d_in[10];
    it_Wlin = (const float*)d_in[11]; it_blin = (const float*)d_in[12];
    us_W1l  = (const float*)d_in[13]; us_W1r  = (const float*)d_in[14]; us_b1   = (const float*)d_in[15];
    us_W2l  = (const float*)d_in[16]; us_W2r  = (const float*)d_in[17]; us_b2   = (const float*)d_in[18];
    us_W3l  = (const float*)d_in[19]; us_W3r  = (const float*)d_in[20]; us_b3   = (const float*)d_in[21];
    us_Wlin = (const float*)d_in[22]; us_blin = (const float*)d_in[23];
  }
  const float* de_W1 = (const float*)d_in[24];
  const float* de_b1 = (const float*)d_in[25];
  const float* de_W2 = (const float*)d_in[26];
  const float* de_b2 = (const float*)d_in[27];

  char* ws = (char*)d_ws;
  int* cnt_pp   = (int*)(ws + 0);          // 400000 B
  int* cnt_pc   = (int*)(ws + 400000);     // 200000 B
  int* ctr      = (int*)(ws + 600000);     // 8 B (2 counters)
  int* start_pp = (int*)(ws + 600256);
  int* fill_pp  = (int*)(ws + 1000256);
  int* start_pc = (int*)(ws + 1400256);
  int* fill_pc  = (int*)(ws + 1600256);
  int* esrc_pp  = (int*)(ws + 1800256);    // 3.2 MB
  int* esrc_pc  = (int*)(ws + 5000256);    // 3.2 MB
  u16* meanb = (u16*)(ws + 8200448);       // 25.6 MB; later reused as ZC
  u16* P1    = (u16*)(ws + 33800448);      // 25.6 MB (p1, then p2 in-place)
  u16* PX    = (u16*)(ws + 59400448);      // 25.6 MB; later reused as ZP
  u16* CX    = (u16*)(ws + 85000448);      // 12.8 MB -> peak ~97.8 MB
  u16* ZP    = PX;                         // PX dead after 4th aggregation
  u16* ZC    = meanb;                      // meanb dead after us-layer3 GEMM

  (void)in_sizes; (void)n_in; (void)out_size; (void)ws_size;

  hipMemsetAsync(d_ws, 0, 600008, stream);  // cnt_pp + cnt_pc + ctrs

  dim3 B(256);
  // CSR build for both graphs
  k_hist<<<dim3((EPP + 255) / 256), B, 0, stream>>>(ei_pp + EPP, EPP, cnt_pp);
  k_hist<<<dim3((EPC + 255) / 256), B, 0, stream>>>(ei_pc + EPC, EPC, cnt_pc);
  k_offsets<<<dim3((NPROD + 255) / 256), B, 0, stream>>>(cnt_pp, NPROD, start_pp, fill_pp, ctr);
  k_offsets<<<dim3((NCUST + 255) / 256), B, 0, stream>>>(cnt_pc, NCUST, start_pc, fill_pc, ctr + 1);
  k_fill<<<dim3((EPP + 255) / 256), B, 0, stream>>>(ei_pp, ei_pp + EPP, EPP, fill_pp, esrc_pp);
  k_fill<<<dim3((EPC + 255) / 256), B, 0, stream>>>(ei_pc, ei_pc + EPC, EPC, fill_pc, esrc_pc);

  dim3 Gp((NPROD + 63) / 64), Gc((NCUST + 63) / 64);
  dim3 Ap(NPROD / 4), Ac(NCUST / 4);

  // mean1 = mean_pp(x_product)  — shared by it-layer1 and us-layer1
  k_agg<true><<<Ap, B, 0, stream>>>(esrc_pp, start_pp, cnt_pp, x_prod, meanb, NPROD);
  k_gemm<128, true, true, true><<<Gp, B, 0, stream>>>(meanb, it_W1l, x_prod, it_W1r, it_b1, P1, NPROD);
  k_gemm<128, true, true, true><<<Gp, B, 0, stream>>>(meanb, us_W1l, x_prod, us_W1r, us_b1, PX, NPROD);
  // mean2 = mean_pp(p1); p2 in-place over P1
  k_agg<false><<<Ap, B, 0, stream>>>(esrc_pp, start_pp, cnt_pp, P1, meanb, NPROD);
  k_gemm<128, true, true, false><<<Gp, B, 0, stream>>>(meanb, it_W2l, P1, it_W2r, it_b2, P1, NPROD);
  // mean_pc1 = mean_pc(x_product); cx
  k_agg<true><<<Ac, B, 0, stream>>>(esrc_pc, start_pc, cnt_pc, x_prod, meanb, NCUST);
  k_gemm<128, true, true, true><<<Gc, B, 0, stream>>>(meanb, us_W2l, x_cust, us_W2r, us_b2, CX, NCUST);
  // mean_pc2 = mean_pc(px)  — last read of PX; ZP may overlay it afterwards
  k_agg<false><<<Ac, B, 0, stream>>>(esrc_pc, start_pc, cnt_pc, PX, meanb, NCUST);
  // z_prod = p2 @ it_Wlin^T + it_blin   (writes into old PX region)
  k_gemm<64, false, false, false><<<Gp, B, 0, stream>>>(P1, it_Wlin, P1, it_Wlin, it_blin, ZP, NPROD);
  // cx2 in-place over CX — last read of meanb; ZC may overlay it afterwards
  k_gemm<128, true, true, false><<<Gc, B, 0, stream>>>(meanb, us_W3l, CX, us_W3r, us_b3, CX, NCUST);
  // z_cust = cx2 @ us_Wlin^T + us_blin  (writes into old meanb region)
  k_gemm<64, false, false, false><<<Gc, B, 0, stream>>>(CX, us_Wlin, CX, us_Wlin, us_blin, ZC, NCUST);
  // decoder -> fp32 output
  k_decoder<<<dim3((ELB + 63) / 64), B, 0, stream>>>(ZC, ZP, eli, de_W1, de_b1, de_W2, de_b2,
                                                     (float*)d_out);
}

// Round 4
// 690.517 us; speedup vs baseline: 1.2205x; 1.2205x over previous
//
#include <hip/hip_runtime.h>
#include <hip/hip_bf16.h>

#define HID   128
#define OUTD  64
#define NPROD 100000
#define NCUST 50000
#define EPP   800000
#define EPC   800000
#define ELB   400000

typedef __bf16 bf16x8 __attribute__((ext_vector_type(8)));
typedef float  f32x4  __attribute__((ext_vector_type(4)));
typedef unsigned short u16;

__device__ __forceinline__ float b2f(u16 u) {
  unsigned int v = ((unsigned int)u) << 16;
  float f; __builtin_memcpy(&f, &v, 4); return f;
}
__device__ __forceinline__ u16 f2b(float f) {
  __hip_bfloat16 h = __float2bfloat16(f);
  u16 u; __builtin_memcpy(&u, &h, 2); return u;
}

union Pack8 { u16 u[8]; int4 v; };

// XOR-swizzled LDS index (elements). Rows of 128 bf16 (256 B); 16 B chunks
// swizzled by row&15 so column-direction ds_read_b128 lands 2-way max (free).
__device__ __forceinline__ int sidx(int row, int chunk) {
  return row * HID + ((chunk ^ (row & 15)) << 3);
}

// ---------------- fp32 -> bf16 cast (8 elems/thread) ----------------
__global__ __launch_bounds__(256) void k_cast(const float* __restrict__ src,
                                              u16* __restrict__ dst, int n8) {
  int i = blockIdx.x * 256 + threadIdx.x;
  if (i >= n8) return;
  float4 a = ((const float4*)src)[2 * i];
  float4 b = ((const float4*)src)[2 * i + 1];
  Pack8 p;
  p.u[0] = f2b(a.x); p.u[1] = f2b(a.y); p.u[2] = f2b(a.z); p.u[3] = f2b(a.w);
  p.u[4] = f2b(b.x); p.u[5] = f2b(b.y); p.u[6] = f2b(b.z); p.u[7] = f2b(b.w);
  ((int4*)dst)[i] = p.v;
}

#define NJOBS 13
struct CastJobs { const float* src[NJOBS]; int n8[NJOBS]; };

// 8 blocks per job; jobs are <=16384 elems (2048 int4).
__global__ __launch_bounds__(256) void k_cast_w(CastJobs jobs, u16* __restrict__ wbuf) {
  int job = blockIdx.x >> 3;
  int idx = (blockIdx.x & 7) * 256 + threadIdx.x;   // int4 index within job
  // dst offset: jobs 0..9 are 16384 elems, 10..12 are 8192
  int off8 = (job < 10) ? job * 2048 : 10 * 2048 + (job - 10) * 1024;
  if (idx >= jobs.n8[job]) return;
  const float* s = jobs.src[job];
  float4 a = ((const float4*)s)[2 * idx];
  float4 b = ((const float4*)s)[2 * idx + 1];
  Pack8 p;
  p.u[0] = f2b(a.x); p.u[1] = f2b(a.y); p.u[2] = f2b(a.z); p.u[3] = f2b(a.w);
  p.u[4] = f2b(b.x); p.u[5] = f2b(b.y); p.u[6] = f2b(b.z); p.u[7] = f2b(b.w);
  ((int4*)wbuf)[off8 + idx] = p.v;
}

// ---------------- CSR build (order-free bucketing) ----------------
__global__ __launch_bounds__(256) void k_hist(const int* __restrict__ dst, int E,
                                              int* __restrict__ cnt) {
  int e = blockIdx.x * 256 + threadIdx.x;
  if (e < E) atomicAdd(&cnt[dst[e]], 1);
}

__global__ __launch_bounds__(256) void k_offsets(const int* __restrict__ cnt, int n,
                                                 int* __restrict__ start,
                                                 int* __restrict__ fill,
                                                 int* __restrict__ ctr) {
  int i = blockIdx.x * 256 + threadIdx.x;
  if (i < n) {
    int s = atomicAdd(ctr, cnt[i]);   // order-free contiguous range per node
    start[i] = s;
    fill[i]  = s;
  }
}

__global__ __launch_bounds__(256) void k_fill(const int* __restrict__ src,
                                              const int* __restrict__ dst, int E,
                                              int* __restrict__ fill,
                                              int* __restrict__ esrc) {
  int e = blockIdx.x * 256 + threadIdx.x;
  if (e < E) {
    int p = atomicAdd(&fill[dst[e]], 1);
    esrc[p] = src[e];
  }
}

// ---------------- mean aggregation: one quarter-wave (16 lanes) per node --------
// Each lane covers 8 feature columns via one dwordx4 (16 B) per edge row.
// 4 nodes per wave -> 4x the load-level parallelism of one-node-per-wave.
__global__ __launch_bounds__(256) void k_agg(const int* __restrict__ esrc,
                                             const int* __restrict__ start,
                                             const int* __restrict__ cnt,
                                             const u16* __restrict__ x,
                                             u16* __restrict__ outm, int n_dst) {
  int node = blockIdx.x * 16 + (threadIdx.x >> 4);
  int l16  = threadIdx.x & 15;
  if (node >= n_dst) return;
  int s0 = start[node], c = cnt[node];
  float acc[8] = {0.f, 0.f, 0.f, 0.f, 0.f, 0.f, 0.f, 0.f};
  for (int j0 = 0; j0 < c; j0 += 16) {
    int nch = min(16, c - j0);
    int eid = (l16 < nch) ? esrc[s0 + j0 + l16] : 0;
    for (int k = 0; k < nch; ++k) {
      int s = __shfl(eid, (threadIdx.x & 48) + k, 64);  // quarter-local broadcast
      Pack8 p;
      p.v = *(const int4*)(x + (size_t)s * HID + l16 * 8);
      #pragma unroll
      for (int t = 0; t < 8; ++t) acc[t] += b2f(p.u[t]);
    }
  }
  float inv = 1.0f / (float)max(c, 1);
  Pack8 o;
  #pragma unroll
  for (int t = 0; t < 8; ++t) o.u[t] = f2b(acc[t] * inv);
  *(int4*)(outm + (size_t)node * HID + l16 * 8) = o.v;
}

// ---------------- fused (dual-K) GEMM: out = act(A1@W1^T [+ A2@W2^T] + bias) ----
// A1 bf16 [M,128]; A2 bf16 (or fp32 when A2F); W* bf16 [BN,128]; bias fp32;
// out bf16 [M,BN]. Block tile 64xBN, 4 waves in N. LDS <= 48 KB.
// In-place (out==A2) safe: each block reads only the rows it writes.
template <int BN, bool DUAL, bool RELU, bool A2F>
__global__ __launch_bounds__(256) void k_gemm(const u16* __restrict__ A1,
                                              const u16* __restrict__ W1,
                                              const void* __restrict__ A2v,
                                              const u16* __restrict__ W2,
                                              const float* __restrict__ bias,
                                              u16* __restrict__ out, int M) {
  __shared__ __align__(16) u16 sA[64 * HID];
  __shared__ __align__(16) u16 sW[BN * HID];
  const int tid  = threadIdx.x;
  const int lane = tid & 63;
  const int wave = tid >> 6;          // 0..3 -> N-group
  const int q    = lane >> 4;
  const int r16  = lane & 15;
  const int m0   = blockIdx.x * 64;
  constexpr int NT = BN / 64;         // 16-col tiles per wave

  f32x4 acc[4][NT];
  #pragma unroll
  for (int i = 0; i < 4; ++i)
    #pragma unroll
    for (int j = 0; j < NT; ++j) {
      acc[i][j][0] = 0.f; acc[i][j][1] = 0.f; acc[i][j][2] = 0.f; acc[i][j][3] = 0.f;
    }

  #pragma unroll
  for (int phase = 0; phase < (DUAL ? 2 : 1); ++phase) {
    const u16* W = phase ? W2 : W1;
    if (phase) __syncthreads();       // phase-0 MFMA reads done before restage
    // stage A tile (64 rows x 16 chunks of 8 elems), guarded at ragged tail
    #pragma unroll
    for (int i = 0; i < 4; ++i) {
      int idx = i * 256 + tid;
      int rr = idx >> 4, c8 = idx & 15;
      int gr = m0 + rr;
      Pack8 p; p.v = make_int4(0, 0, 0, 0);
      if (gr < M) {
        if (phase == 0 || !A2F) {
          const u16* A = phase ? (const u16*)A2v : A1;
          p.v = *(const int4*)(A + (size_t)gr * HID + c8 * 8);
        } else {
          const float* A = (const float*)A2v;
          const float* s = A + (size_t)gr * HID + c8 * 8;
          float4 f0 = ((const float4*)s)[0], f1 = ((const float4*)s)[1];
          p.u[0] = f2b(f0.x); p.u[1] = f2b(f0.y); p.u[2] = f2b(f0.z); p.u[3] = f2b(f0.w);
          p.u[4] = f2b(f1.x); p.u[5] = f2b(f1.y); p.u[6] = f2b(f1.z); p.u[7] = f2b(f1.w);
        }
      }
      *(int4*)(sA + sidx(rr, c8)) = p.v;
    }
    // stage W tile (BN rows x 16 chunks), bf16 copy
    #pragma unroll
    for (int i = 0; i < BN / 16; ++i) {
      int idx = i * 256 + tid;
      int rr = idx >> 4, c8 = idx & 15;
      *(int4*)(sW + sidx(rr, c8)) = *(const int4*)(W + (size_t)rr * HID + c8 * 8);
    }
    __syncthreads();
    #pragma unroll
    for (int ks = 0; ks < 4; ++ks) {
      int chunk = ks * 4 + q;         // k = ks*32 + q*8 + j
      bf16x8 a[4], b[NT];
      #pragma unroll
      for (int mi = 0; mi < 4; ++mi)
        a[mi] = *(const bf16x8*)(sA + sidx(mi * 16 + r16, chunk));
      #pragma unroll
      for (int ni = 0; ni < NT; ++ni)
        b[ni] = *(const bf16x8*)(sW + sidx(wave * (16 * NT) + ni * 16 + r16, chunk));
      #pragma unroll
      for (int mi = 0; mi < 4; ++mi)
        #pragma unroll
        for (int ni = 0; ni < NT; ++ni)
          acc[mi][ni] = __builtin_amdgcn_mfma_f32_16x16x32_bf16(a[mi], b[ni], acc[mi][ni], 0, 0, 0);
    }
  }
  // epilogue: fp32 bias (+ReLU), bf16 store. C/D: col=lane&15, row=(lane>>4)*4+r.
  #pragma unroll
  for (int ni = 0; ni < NT; ++ni) {
    int col = wave * (16 * NT) + ni * 16 + r16;
    float bv = bias[col];
    #pragma unroll
    for (int mi = 0; mi < 4; ++mi) {
      #pragma unroll
      for (int r = 0; r < 4; ++r) {
        int gr = m0 + mi * 16 + q * 4 + r;
        if (gr < M) {
          float v = acc[mi][ni][r] + bv;
          if (RELU) v = fmaxf(v, 0.f);
          out[(size_t)gr * BN + col] = f2b(v);
        }
      }
    }
  }
}

// ---------------- edge decoder: out = w2 . relu(W1 @ [zc[row]|zp[col]] + b1) + b2 ----
// zc/zp bf16 [.,64]; W1 bf16 [64,128]; b1,w2,b2 fp32; out fp32 [ELB].
__global__ __launch_bounds__(256) void k_decoder(const u16* __restrict__ zc,
                                                 const u16* __restrict__ zp,
                                                 const int* __restrict__ eli,
                                                 const u16* __restrict__ W1,
                                                 const float* __restrict__ b1,
                                                 const float* __restrict__ w2,
                                                 const float* __restrict__ b2,
                                                 float* __restrict__ out) {
  __shared__ __align__(16) u16 sH[64 * HID];
  __shared__ __align__(16) u16 sW[64 * HID];
  const int tid  = threadIdx.x;
  const int lane = tid & 63;
  const int wave = tid >> 6;
  const int q    = lane >> 4;
  const int r16  = lane & 15;
  const int e0   = blockIdx.x * 64;
  // stage W1 (64x128) bf16
  #pragma unroll
  for (int i = 0; i < 4; ++i) {
    int idx = i * 256 + tid;
    int rr = idx >> 4, c8 = idx & 15;
    *(int4*)(sW + sidx(rr, c8)) = *(const int4*)(W1 + (size_t)rr * HID + c8 * 8);
  }
  // stage H: 64 edges x (64 zc | 64 zp), bf16 gather
  #pragma unroll
  for (int i = 0; i < 4; ++i) {
    int idx = i * 256 + tid;
    int rr = idx >> 4, c8 = idx & 15;
    int e = e0 + rr;
    int4 v = make_int4(0, 0, 0, 0);
    if (e < ELB) {
      if (c8 < 8) {
        int rI = eli[e];
        v = *(const int4*)(zc + (size_t)rI * OUTD + c8 * 8);
      } else {
        int cI = eli[ELB + e];
        v = *(const int4*)(zp + (size_t)cI * OUTD + (c8 - 8) * 8);
      }
    }
    *(int4*)(sH + sidx(rr, c8)) = v;
  }
  __syncthreads();
  f32x4 acc[4];
  #pragma unroll
  for (int ni = 0; ni < 4; ++ni) { acc[ni][0]=0.f; acc[ni][1]=0.f; acc[ni][2]=0.f; acc[ni][3]=0.f; }
  #pragma unroll
  for (int ks = 0; ks < 4; ++ks) {
    int chunk = ks * 4 + q;
    bf16x8 a = *(const bf16x8*)(sH + sidx(wave * 16 + r16, chunk));
    #pragma unroll
    for (int ni = 0; ni < 4; ++ni) {
      bf16x8 b = *(const bf16x8*)(sW + sidx(ni * 16 + r16, chunk));
      acc[ni] = __builtin_amdgcn_mfma_f32_16x16x32_bf16(a, b, acc[ni], 0, 0, 0);
    }
  }
  float vs[4] = {0.f, 0.f, 0.f, 0.f};
  #pragma unroll
  for (int ni = 0; ni < 4; ++ni) {
    int col = ni * 16 + r16;
    float bb = b1[col];
    float ww = w2[col];
    #pragma unroll
    for (int r = 0; r < 4; ++r) {
      float t = fmaxf(acc[ni][r] + bb, 0.f);
      vs[r] += t * ww;
    }
  }
  #pragma unroll
  for (int r = 0; r < 4; ++r) {
    vs[r] += __shfl_xor(vs[r], 1, 64);
    vs[r] += __shfl_xor(vs[r], 2, 64);
    vs[r] += __shfl_xor(vs[r], 4, 64);
    vs[r] += __shfl_xor(vs[r], 8, 64);
  }
  if (r16 == 0) {
    float bb2 = b2[0];
    #pragma unroll
    for (int r = 0; r < 4; ++r) {
      int e = e0 + wave * 16 + q * 4 + r;
      if (e < ELB) out[e] = vs[r] + bb2;
    }
  }
}

extern "C" void kernel_launch(void* const* d_in, const int* in_sizes, int n_in,
                              void* d_out, int out_size, void* d_ws, size_t ws_size,
                              hipStream_t stream) {
  const float* x_prod = (const float*)d_in[0];
  const float* x_cust = (const float*)d_in[1];
  const int* ei_pp    = (const int*)d_in[2];
  const int* ei_pc    = (const int*)d_in[3];
  const int* eli      = (const int*)d_in[4];

  // Input-order detection: dict order has it_W1r (16384 elems) at index 6;
  // reference-signature order has it_b1 (128) there.
  const float *it_W1l, *it_W1r, *it_b1, *it_W2l, *it_W2r, *it_b2, *it_Wlin, *it_blin;
  const float *us_W1l, *us_W1r, *us_b1, *us_W2l, *us_W2r, *us_b2;
  const float *us_W3l, *us_W3r, *us_b3, *us_Wlin, *us_blin;
  if (in_sizes[6] == 128) {   // signature order (Wl, b, Wr)
    it_W1l  = (const float*)d_in[5];  it_b1   = (const float*)d_in[6];  it_W1r  = (const float*)d_in[7];
    it_W2l  = (const float*)d_in[8];  it_b2   = (const float*)d_in[9];  it_W2r  = (const float*)d_in[10];
    it_Wlin = (const float*)d_in[11]; it_blin = (const float*)d_in[12];
    us_W1l  = (const float*)d_in[13]; us_b1   = (const float*)d_in[14]; us_W1r  = (const float*)d_in[15];
    us_W2l  = (const float*)d_in[16]; us_b2   = (const float*)d_in[17]; us_W2r  = (const float*)d_in[18];
    us_W3l  = (const float*)d_in[19]; us_b3   = (const float*)d_in[20]; us_W3r  = (const float*)d_in[21];
    us_Wlin = (const float*)d_in[22]; us_blin = (const float*)d_in[23];
  } else {                    // setup_inputs dict order (Wl, Wr, b)
    it_W1l  = (const float*)d_in[5];  it_W1r  = (const float*)d_in[6];  it_b1   = (const float*)d_in[7];
    it_W2l  = (const float*)d_in[8];  it_W2r  = (const float*)d_in[9];  it_b2   = (const float*)d_in[10];
    it_Wlin = (const float*)d_in[11]; it_blin = (const float*)d_in[12];
    us_W1l  = (const float*)d_in[13]; us_W1r  = (const float*)d_in[14]; us_b1   = (const float*)d_in[15];
    us_W2l  = (const float*)d_in[16]; us_W2r  = (const float*)d_in[17]; us_b2   = (const float*)d_in[18];
    us_W3l  = (const float*)d_in[19]; us_W3r  = (const float*)d_in[20]; us_b3   = (const float*)d_in[21];
    us_Wlin = (const float*)d_in[22]; us_blin = (const float*)d_in[23];
  }
  const float* de_W1 = (const float*)d_in[24];
  const float* de_b1 = (const float*)d_in[25];
  const float* de_W2 = (const float*)d_in[26];
  const float* de_b2 = (const float*)d_in[27];

  char* ws = (char*)d_ws;
  int* cnt_pp   = (int*)(ws + 0);          // 400000 B
  int* cnt_pc   = (int*)(ws + 400000);     // 200000 B
  int* ctr      = (int*)(ws + 600000);     // 8 B
  int* start_pp = (int*)(ws + 600256);
  int* fill_pp  = (int*)(ws + 1000256);
  int* start_pc = (int*)(ws + 1400256);
  int* fill_pc  = (int*)(ws + 1600256);
  int* esrc_pp  = (int*)(ws + 1800256);    // 3.2 MB
  int* esrc_pc  = (int*)(ws + 5000256);    // 3.2 MB
  u16* wbuf  = (u16*)(ws + 8200448);       // 368 KB bf16 weights
  u16* XPB   = (u16*)(ws + 8577280);       // 25.6 MB bf16 x_prod; becomes PX in-place
  u16* meanb = (u16*)(ws + 34177280);      // 25.6 MB mean (prod rows); later ZP
  u16* P1    = (u16*)(ws + 59777280);      // 25.6 MB (p1, then p2 in-place)
  u16* meanc = (u16*)(ws + 85377280);      // 12.8 MB mean (cust rows); later ZC
  u16* CX    = (u16*)(ws + 98177280);      // 12.8 MB -> peak ~111 MB
  u16* PX = XPB;                           // us-layer1 out, in-place over bf16 x_prod
  u16* ZP = meanb;                         // meanb dead after it-layer2 GEMM
  u16* ZC = meanc;                         // meanc dead after us-layer3 GEMM

  // bf16 weight table offsets (elements) in wbuf, matching k_cast_w job order
  u16* w_it1l = wbuf + 0 * 16384;  u16* w_it1r = wbuf + 1 * 16384;
  u16* w_it2l = wbuf + 2 * 16384;  u16* w_it2r = wbuf + 3 * 16384;
  u16* w_us1l = wbuf + 4 * 16384;  u16* w_us1r = wbuf + 5 * 16384;
  u16* w_us2l = wbuf + 6 * 16384;  u16* w_us2r = wbuf + 7 * 16384;
  u16* w_us3l = wbuf + 8 * 16384;  u16* w_us3r = wbuf + 9 * 16384;
  u16* w_itlin = wbuf + 10 * 16384;
  u16* w_uslin = wbuf + 10 * 16384 + 8192;
  u16* w_deW1  = wbuf + 10 * 16384 + 2 * 8192;

  (void)n_in; (void)out_size; (void)ws_size;

  hipMemsetAsync(d_ws, 0, 600008, stream);  // cnt_pp + cnt_pc + ctrs

  dim3 B(256);
  // casts
  k_cast<<<dim3((NPROD * HID / 8 + 255) / 256), B, 0, stream>>>(x_prod, XPB, NPROD * HID / 8);
  CastJobs jobs;
  jobs.src[0] = it_W1l;  jobs.src[1] = it_W1r;  jobs.src[2] = it_W2l;  jobs.src[3] = it_W2r;
  jobs.src[4] = us_W1l;  jobs.src[5] = us_W1r;  jobs.src[6] = us_W2l;  jobs.src[7] = us_W2r;
  jobs.src[8] = us_W3l;  jobs.src[9] = us_W3r;
  jobs.src[10] = it_Wlin; jobs.src[11] = us_Wlin; jobs.src[12] = de_W1;
  for (int i = 0; i < 10; ++i) jobs.n8[i] = 2048;
  for (int i = 10; i < 13; ++i) jobs.n8[i] = 1024;
  k_cast_w<<<dim3(NJOBS * 8), B, 0, stream>>>(jobs, wbuf);

  // CSR build for both graphs
  k_hist<<<dim3((EPP + 255) / 256), B, 0, stream>>>(ei_pp + EPP, EPP, cnt_pp);
  k_hist<<<dim3((EPC + 255) / 256), B, 0, stream>>>(ei_pc + EPC, EPC, cnt_pc);
  k_offsets<<<dim3((NPROD + 255) / 256), B, 0, stream>>>(cnt_pp, NPROD, start_pp, fill_pp, ctr);
  k_offsets<<<dim3((NCUST + 255) / 256), B, 0, stream>>>(cnt_pc, NCUST, start_pc, fill_pc, ctr + 1);
  k_fill<<<dim3((EPP + 255) / 256), B, 0, stream>>>(ei_pp, ei_pp + EPP, EPP, fill_pp, esrc_pp);
  k_fill<<<dim3((EPC + 255) / 256), B, 0, stream>>>(ei_pc, ei_pc + EPC, EPC, fill_pc, esrc_pc);

  dim3 Gp((NPROD + 63) / 64), Gc((NCUST + 63) / 64);
  dim3 App((NPROD + 15) / 16), Apc((NCUST + 15) / 16);

  // mean_pp1 and mean_pc1 from bf16 x_prod (xp last read by us-layer1 GEMM)
  k_agg<<<App, B, 0, stream>>>(esrc_pp, start_pp, cnt_pp, XPB, meanb, NPROD);
  k_agg<<<Apc, B, 0, stream>>>(esrc_pc, start_pc, cnt_pc, XPB, meanc, NCUST);
  k_gemm<128, true, true, false><<<Gp, B, 0, stream>>>(meanb, w_it1l, XPB, w_it1r, it_b1, P1, NPROD);
  k_gemm<128, true, true, false><<<Gp, B, 0, stream>>>(meanb, w_us1l, XPB, w_us1r, us_b1, PX, NPROD);
  // mean_pp2 = mean_pp(p1); p2 in-place over P1
  k_agg<<<App, B, 0, stream>>>(esrc_pp, start_pp, cnt_pp, P1, meanb, NPROD);
  k_gemm<128, true, true, false><<<Gp, B, 0, stream>>>(meanb, w_it2l, P1, w_it2r, it_b2, P1, NPROD);
  // cx = relu(mean_pc1@W2l + x_cust(fp32)@W2r + b2)
  k_gemm<128, true, true, true><<<Gc, B, 0, stream>>>(meanc, w_us2l, x_cust, w_us2r, us_b2, CX, NCUST);
  // mean_pc2 = mean_pc(px) -> meanc (meanc consumed above)
  k_agg<<<Apc, B, 0, stream>>>(esrc_pc, start_pc, cnt_pc, PX, meanc, NCUST);
  // cx2 in-place over CX
  k_gemm<128, true, true, false><<<Gc, B, 0, stream>>>(meanc, w_us3l, CX, w_us3r, us_b3, CX, NCUST);
  // projections (overlay dead buffers)
  k_gemm<64, false, false, false><<<Gp, B, 0, stream>>>(P1, w_itlin, nullptr, nullptr, it_blin, ZP, NPROD);
  k_gemm<64, false, false, false><<<Gc, B, 0, stream>>>(CX, w_uslin, nullptr, nullptr, us_blin, ZC, NCUST);
  // decoder -> fp32 output
  k_decoder<<<dim3((ELB + 63) / 64), B, 0, stream>>>(ZC, ZP, eli, w_deW1, de_b1, de_W2, de_b2,
                                                     (float*)d_out);
}